// Round 3
// baseline (135.727 us; speedup 1.0000x reference)
//
#include <hip/hip_runtime.h>
#include <hip/hip_bf16.h>

// Block-circulant conv == GEMM  out[b,oc,r] = sum_k A[b*1024+r, k] * B[k, oc]
//   A = im2col(x) per batch, contiguous (1024, 2304) view (reference's reshape).
//   B[k,oc] = w[oc>>6][k>>6][((oc&63)-(k&63))&63]  (circulant expansion)
//
// R3: (1) XOR-swizzled LDS (kills the 16-way bank conflicts R2 measured:
//     1.06e7 conflict cycles); swizzle is applied on the *global source*
//     address since global_load_lds pins lane->base+l*16.
//     (2) double-buffered K-loop with raw s_waitcnt vmcnt(4) + s_barrier so
//     the q+1 prefetch stays in flight across the barrier (1 block/CU).
//     (3) pre-kernels merged into one dispatch, im2col does 16B stores.

#define QK 2304
#define MROWS 8192
#define NOC 512
#define QB 36

typedef __attribute__((ext_vector_type(8))) short short8;
typedef __attribute__((ext_vector_type(4))) float floatx4;
typedef __attribute__((ext_vector_type(8))) ushort ushort8;

__device__ __forceinline__ ushort f2bf(float f) {
    __hip_bfloat16 h = __float2bfloat16(f);
    return *reinterpret_cast<ushort*>(&h);
}

__device__ __forceinline__ void async16(const void* g, void* l) {
    __builtin_amdgcn_global_load_lds((const __attribute__((address_space(1))) void*)g,
                                     (__attribute__((address_space(3))) void*)l, 16, 0, 0);
}

// ---------------- merged pre-kernel: im2col + circulant expand ----------------
#define IM2COL_BLOCKS 9216   // 9216*256 = 8192 rows * 288 stores
#define EXPAND_BLOCKS 576    // 576*256  = 512 rows * 288 stores

__global__ __launch_bounds__(256) void bcc_prep(const float* __restrict__ x,
                                                const float* __restrict__ w,
                                                ushort* __restrict__ wsA,
                                                ushort* __restrict__ wsB) {
    if (blockIdx.x < IM2COL_BLOCKS) {
        int t = blockIdx.x * 256 + threadIdx.x;      // 0..2359295
        int m = t / 288;                             // row 0..8191
        int o = t - m * 288;                         // 16B-store index in row
        int b = m >> 10, r = m & 1023;
        const float* xb = x + (size_t)b * (256 * 32 * 32);
        int j0 = r * QK + o * 8;
        ushort8 u;
        #pragma unroll
        for (int e = 0; e < 8; ++e) {
            int j = j0 + e;
            int feat = j >> 10, loc = j & 1023;
            int c = feat / 9, kk = feat - c * 9;
            int di = kk / 3, dj = kk - di * 3;
            int hi = (loc >> 5) + di - 1, wi = (loc & 31) + dj - 1;
            float v = 0.f;
            if ((unsigned)hi < 32u && (unsigned)wi < 32u)
                v = xb[(c * 32 + hi) * 32 + wi];
            u[e] = f2bf(v);
        }
        *(ushort8*)&wsA[(size_t)m * QK + o * 8] = u;
    } else {
        int t = (blockIdx.x - IM2COL_BLOCKS) * 256 + threadIdx.x;  // 0..147455
        int n = t / 288;
        int o = t - n * 288;
        int p = n >> 6, tt = n & 63;
        int k0 = o * 8;
        ushort8 u;
        #pragma unroll
        for (int e = 0; e < 8; ++e) {
            int k = k0 + e;
            int q = k >> 6, s = k & 63;
            u[e] = f2bf(w[(p * QB + q) * 64 + ((tt - s) & 63)]);
        }
        *(ushort8*)&wsB[(size_t)n * QK + k0] = u;
    }
}

// ---------------- main GEMM: 128x128 tile, BK=64, 8 waves, dbuf ----------------
__global__ __launch_bounds__(512) void bcc_mfma(const ushort* __restrict__ A,
                                                const ushort* __restrict__ Bm,
                                                float* __restrict__ out) {
    __shared__ ushort As[2][128 * 64];   // 16 KB each, XOR-swizzled chunks
    __shared__ ushort Bs[2][128 * 64];

    const int tid = threadIdx.x;
    const int l  = tid & 63, w = tid >> 6;   // 8 waves
    const int wm = w >> 2, wn = w & 3;       // wave tile: 64m x 32n
    const int m0w = wm * 64, n0w = wn * 32;
    const int n0 = blockIdx.x * 128;
    const int m0 = blockIdx.y * 128;
    const int b  = m0 >> 10, r0 = m0 & 1023;

    const int lr = l & 15, lq = l >> 4;      // quarter-wave split
    const int lrow = l >> 3;                  // staging row within 8-group
    const int lchunk = (l & 7) ^ (lrow & 7);  // swizzled global source chunk
    const int lkoff = lchunk * 8;             // shorts

    floatx4 acc[4][2];
    #pragma unroll
    for (int i = 0; i < 4; ++i)
        #pragma unroll
        for (int j = 0; j < 2; ++j) acc[i][j] = (floatx4){0.f, 0.f, 0.f, 0.f};

    // --- staging: 4 async16 per wave per buffer (2 A + 2 B) ---
    auto stage = [&](int q, int buf) {
        const int kb = q * 64;
        #pragma unroll
        for (int t = 0; t < 2; ++t) {
            int row8 = w * 16 + t * 8;
            async16(A  + ((size_t)(m0 + row8 + lrow) * QK + kb + lkoff),
                    &As[buf][row8 * 64]);
            async16(Bm + ((size_t)(n0 + row8 + lrow) * QK + kb + lkoff),
                    &Bs[buf][row8 * 64]);
        }
    };

    stage(0, 0);
    int buf = 0;
    for (int q = 0; q < QB; ++q) {
        if (q + 1 < QB) {
            stage(q + 1, buf ^ 1);
            asm volatile("s_waitcnt vmcnt(4)" ::: "memory");
        } else {
            asm volatile("s_waitcnt vmcnt(0)" ::: "memory");
        }
        __builtin_amdgcn_s_barrier();
        asm volatile("" ::: "memory");

        #pragma unroll
        for (int ks = 0; ks < 2; ++ks) {
            short8 av[4], bv[2];
            const int ca = ks * 4 + lq;      // logical 16B chunk
            #pragma unroll
            for (int i = 0; i < 4; ++i) {
                int Ra = m0w + i * 16 + lr;
                av[i] = *(const short8*)&As[buf][Ra * 64 + ((ca ^ (Ra & 7)) * 8)];
            }
            #pragma unroll
            for (int j = 0; j < 2; ++j) {
                int Rb = n0w + j * 16 + lr;
                bv[j] = *(const short8*)&Bs[buf][Rb * 64 + ((ca ^ (Rb & 7)) * 8)];
            }
            // operand-swapped: D rows = oc, cols = r (r-contiguous stores)
            #pragma unroll
            for (int i = 0; i < 4; ++i)
                #pragma unroll
                for (int j = 0; j < 2; ++j)
                    acc[i][j] = __builtin_amdgcn_mfma_f32_16x16x32_bf16(bv[j], av[i], acc[i][j], 0, 0, 0);
        }

        asm volatile("" ::: "memory");
        __builtin_amdgcn_s_barrier();
        buf ^= 1;
    }

    // epilogue: out[b][oc][r]
    #pragma unroll
    for (int i = 0; i < 4; ++i) {
        int rr = r0 + m0w + i * 16 + lr;
        #pragma unroll
        for (int j = 0; j < 2; ++j) {
            #pragma unroll
            for (int e = 0; e < 4; ++e) {
                int oc = n0 + n0w + j * 16 + lq * 4 + e;
                out[((size_t)b * NOC + oc) * 1024 + rr] = acc[i][j][e];
            }
        }
    }
}

// ---------------- round-1 fp32 fallback (ws too small) ----------------
__global__ __launch_bounds__(256) void bcc_gemm_f32(
    const float* __restrict__ x, const float* __restrict__ w,
    float* __restrict__ out) {
    __shared__ float Asf[64][68];
    __shared__ float Wsf[64][68];
    const int tid = threadIdx.x;
    const int tn = tid & 15, tm = tid >> 4;
    const int p = blockIdx.x;
    const int m0 = blockIdx.y * 64;
    const int b = m0 >> 10, r0 = m0 & 1023;
    const float* xb = x + (size_t)b * (256 * 32 * 32);
    float acc[4][4] = {};
    for (int q = 0; q < QB; ++q) {
        #pragma unroll
        for (int i = 0; i < 16; ++i) {
            int idx = i * 256 + tid;
            int s = idx & 63, mm = idx >> 6;
            int flat = (r0 + mm) * QK + q * 64 + s;
            int feat = flat >> 10, loc = flat & 1023;
            int c = feat / 9, kk = feat - c * 9;
            int hi = (loc >> 5) + (kk / 3) - 1;
            int wi = (loc & 31) + (kk % 3) - 1;
            float v = 0.0f;
            if ((unsigned)hi < 32u && (unsigned)wi < 32u)
                v = xb[(c * 32 + hi) * 32 + wi];
            Asf[mm][s] = v;
        }
        const float* wb = w + (p * QB + q) * 64;
        #pragma unroll
        for (int i = 0; i < 16; ++i) {
            int idx = i * 256 + tid;
            int t = idx & 63, s = idx >> 6;
            Wsf[s][t] = wb[(t - s) & 63];
        }
        __syncthreads();
        #pragma unroll
        for (int s0 = 0; s0 < 64; s0 += 4) {
            float4 a4[4], b4[4];
            #pragma unroll
            for (int i2 = 0; i2 < 4; ++i2)
                a4[i2] = *(const float4*)&Asf[tm * 4 + i2][s0];
            #pragma unroll
            for (int ss = 0; ss < 4; ++ss)
                b4[ss] = *(const float4*)&Wsf[s0 + ss][tn * 4];
            #pragma unroll
            for (int i2 = 0; i2 < 4; ++i2) {
                const float* av = (const float*)&a4[i2];
                #pragma unroll
                for (int ss = 0; ss < 4; ++ss) {
                    float a = av[ss];
                    acc[i2][0] += a * b4[ss].x;
                    acc[i2][1] += a * b4[ss].y;
                    acc[i2][2] += a * b4[ss].z;
                    acc[i2][3] += a * b4[ss].w;
                }
            }
        }
        __syncthreads();
    }
    float* outb = out + (size_t)b * NOC * 1024;
    const int r_base = r0 + tm * 4;
    #pragma unroll
    for (int j = 0; j < 4; ++j) {
        int oc = p * 64 + tn * 4 + j;
        float4 v = make_float4(acc[0][j], acc[1][j], acc[2][j], acc[3][j]);
        *(float4*)&outb[(size_t)oc * 1024 + r_base] = v;
    }
}

extern "C" void kernel_launch(void* const* d_in, const int* in_sizes, int n_in,
                              void* d_out, int out_size, void* d_ws, size_t ws_size,
                              hipStream_t stream) {
    const float* x = (const float*)d_in[0];
    const float* w = (const float*)d_in[1];
    float* out = (float*)d_out;

    const size_t bytesA = (size_t)MROWS * QK * sizeof(ushort);  // 37,748,736
    const size_t bytesB = (size_t)NOC * QK * sizeof(ushort);    //  2,359,296

    if (ws_size >= bytesA + bytesB) {
        ushort* wsA = (ushort*)d_ws;
        ushort* wsB = (ushort*)((char*)d_ws + bytesA);
        bcc_prep<<<IM2COL_BLOCKS + EXPAND_BLOCKS, 256, 0, stream>>>(x, w, wsA, wsB);
        bcc_mfma<<<dim3(NOC / 128, MROWS / 128), 512, 0, stream>>>(wsA, wsB, out);
    } else {
        bcc_gemm_f32<<<dim3(8, MROWS / 64), 256, 0, stream>>>(x, w, out);
    }
}

// Round 5
// 105.386 us; speedup vs baseline: 1.2879x; 1.2879x over previous
//
#include <hip/hip_runtime.h>
#include <hip/hip_bf16.h>

// Block-circulant conv == GEMM  out[b,oc,r] = sum_k A[b*1024+r, k] * B[k, oc]
//   A = im2col(x) per batch, contiguous (1024, 2304) view (reference reshape).
//   B[k,oc] = w[oc>>6][k>>6][((oc&63)-(k&63))&63]  (circulant expansion)
//
// R5: fix R4's OOB crash in prep — the shifted-copy read x[c*1024+loc0+off]
//     goes out of bounds at array extremes (src=-1 .. src=262144+2). Now
//     per-element loads with clamped-safe addresses + validity mask; lanes
//     stay address-contiguous so coalescing is preserved.
//     GEMM unchanged from R4: 64x64 wave tiles, 2-way k-interleave with
//     LDS-combine, XOR-swizzled LDS, dbuf + raw vmcnt(4) pipeline.

#define QK 2304
#define MROWS 8192
#define NOC 512
#define QB 36

typedef __attribute__((ext_vector_type(8))) short short8;
typedef __attribute__((ext_vector_type(4))) float floatx4;

__device__ __forceinline__ ushort f2bf(float f) {
    __hip_bfloat16 h = __float2bfloat16(f);
    return *reinterpret_cast<ushort*>(&h);
}

__device__ __forceinline__ void async16(const void* g, void* l) {
    __builtin_amdgcn_global_load_lds((const __attribute__((address_space(1))) void*)g,
                                     (__attribute__((address_space(3))) void*)l, 16, 0, 0);
}

// ---------------- prep: A im2col (shifted copy) + B circulant expand ----------------
#define PREP_A_BLOCKS 18432   // 8 b * 2304 feat
#define PREP_B_BLOCKS 576     // 512 rows * 288 8-elem chunks / 256

__global__ __launch_bounds__(256) void bcc_prep(const float* __restrict__ x,
                                                const float* __restrict__ w,
                                                ushort* __restrict__ wsA,
                                                ushort* __restrict__ wsB) {
    if (blockIdx.x < PREP_A_BLOCKS) {
        const int bb   = blockIdx.x / 2304;           // batch (scalar)
        const int feat = blockIdx.x - bb * 2304;      // 0..2303 (scalar)
        const int c  = feat / 9, kk = feat - c * 9;
        const int di = kk / 3, dj = kk - di * 3;
        const int off = (di - 1) * 32 + (dj - 1);
        const int loc0 = threadIdx.x * 4;             // 4 elems/thread
        const float* xb = x + (size_t)bb * 262144;

        const bool row_ok = (unsigned)((loc0 >> 5) + di - 1) < 32u;
        const int base = c * 1024 + loc0 + off;
        ushort u[4];
        #pragma unroll
        for (int e = 0; e < 4; ++e) {
            int idx = base + e;
            int safe = idx < 0 ? 0 : (idx > 262143 ? 262143 : idx);
            float v = xb[safe];
            int wi = ((loc0 + e) & 31) + dj - 1;
            bool ok = row_ok && ((unsigned)wi < 32u);
            u[e] = f2bf(ok ? v : 0.f);
        }
        *(ushort4*)&wsA[((size_t)bb * 2304 + feat) * 1024 + loc0] =
            make_ushort4(u[0], u[1], u[2], u[3]);
    } else {
        int t = (blockIdx.x - PREP_A_BLOCKS) * 256 + threadIdx.x;  // 0..147455
        int n = t / 288;
        int o = t - n * 288;
        int p = n >> 6, tt = n & 63;
        int k0 = o * 8;
        ushort u[8];
        #pragma unroll
        for (int e = 0; e < 8; ++e) {
            int k = k0 + e;
            int q = k >> 6, s = k & 63;
            u[e] = f2bf(w[(p * QB + q) * 64 + ((tt - s) & 63)]);
        }
        *(ushort4*)&wsB[(size_t)n * QK + k0]     = make_ushort4(u[0], u[1], u[2], u[3]);
        *(ushort4*)&wsB[(size_t)n * QK + k0 + 4] = make_ushort4(u[4], u[5], u[6], u[7]);
    }
}

// ---------------- main GEMM: 128x128 tile, 8 waves, 64x64 wave-tiles,
// ---------------- k-interleaved (2-way), dbuf + raw vmcnt(4) pipeline ------
__global__ __launch_bounds__(512) void bcc_mfma(const ushort* __restrict__ A,
                                                const ushort* __restrict__ Bm,
                                                float* __restrict__ out) {
    __shared__ ushort smem[2][2][128 * 64];   // [A/B][buf][row*64+chunk] 64 KB

    const int tid = threadIdx.x;
    const int l = tid & 63, w = tid >> 6;      // 8 waves
    const int t3 = w & 3, ks = w >> 2;         // tile id, k-half
    const int wm = t3 & 1, wn = t3 >> 1;       // 2x2 grid of 64x64 tiles

    // XCD-affinity decode: 4 blocks sharing an A-tile -> same (lin&7) == XCD
    const int lin = blockIdx.x;                // 0..255
    const int n_idx = (lin >> 3) & 3;
    const int m_idx = ((lin >> 5) << 3) | (lin & 7);
    const int n0 = n_idx * 128;
    const int m0 = m_idx * 128;
    const int b  = m0 >> 10, r0 = m0 & 1023;

    const int lr = l & 15, lq = l >> 4;        // quarter-wave split
    const int lrow = l >> 3;                   // staging row in 8-group
    const int lkoff = ((l & 7) ^ (lrow & 7)) * 8;  // swizzled source chunk

    floatx4 acc[4][4];
    #pragma unroll
    for (int i = 0; i < 4; ++i)
        #pragma unroll
        for (int j = 0; j < 4; ++j) acc[i][j] = (floatx4){0.f, 0.f, 0.f, 0.f};

    auto stage = [&](int q, int buf) {
        const int kb = q * 64;
        #pragma unroll
        for (int t = 0; t < 2; ++t) {
            int row8 = w * 16 + t * 8;
            async16(A  + ((size_t)(m0 + row8 + lrow) * QK + kb + lkoff),
                    &smem[0][buf][row8 * 64]);
            async16(Bm + ((size_t)(n0 + row8 + lrow) * QK + kb + lkoff),
                    &smem[1][buf][row8 * 64]);
        }
    };

    stage(0, 0);
    int buf = 0;
    const int ca = ks * 4 + lq;                // logical 16B chunk (k-half)
    for (int q = 0; q < QB; ++q) {
        if (q + 1 < QB) {
            stage(q + 1, buf ^ 1);
            asm volatile("s_waitcnt vmcnt(4)" ::: "memory");
        } else {
            asm volatile("s_waitcnt vmcnt(0)" ::: "memory");
        }
        __builtin_amdgcn_s_barrier();
        asm volatile("" ::: "memory");

        short8 av[4], bv[4];
        #pragma unroll
        for (int i = 0; i < 4; ++i) {
            int Ra = wm * 64 + i * 16 + lr;
            av[i] = *(const short8*)&smem[0][buf][Ra * 64 + ((ca ^ (Ra & 7)) * 8)];
        }
        #pragma unroll
        for (int j = 0; j < 4; ++j) {
            int Rb = wn * 64 + j * 16 + lr;
            bv[j] = *(const short8*)&smem[1][buf][Rb * 64 + ((ca ^ (Rb & 7)) * 8)];
        }
        // operand-swapped: D rows = oc, cols = r (r-contiguous stores)
        #pragma unroll
        for (int i = 0; i < 4; ++i)
            #pragma unroll
            for (int j = 0; j < 4; ++j)
                acc[i][j] = __builtin_amdgcn_mfma_f32_16x16x32_bf16(bv[j], av[i], acc[i][j], 0, 0, 0);

        asm volatile("" ::: "memory");
        __builtin_amdgcn_s_barrier();
        buf ^= 1;
    }

    // ---- combine k-halves through LDS, then store ----
    __syncthreads();
    float* fsm = (float*)&smem[0][0][0];       // 64 KB = 16384 floats
    if (ks == 1) {
        #pragma unroll
        for (int i = 0; i < 4; ++i)
            #pragma unroll
            for (int j = 0; j < 4; ++j)
                *(floatx4*)&fsm[t3 * 4096 + (i * 4 + j) * 256 + l * 4] = acc[i][j];
    }
    __syncthreads();
    if (ks == 0) {
        #pragma unroll
        for (int i = 0; i < 4; ++i) {
            int rr = r0 + wm * 64 + i * 16 + lr;
            #pragma unroll
            for (int j = 0; j < 4; ++j) {
                floatx4 o4 = *(const floatx4*)&fsm[t3 * 4096 + (i * 4 + j) * 256 + l * 4];
                #pragma unroll
                for (int e = 0; e < 4; ++e) {
                    int oc = n0 + wn * 64 + j * 16 + lq * 4 + e;
                    out[((size_t)b * NOC + oc) * 1024 + rr] = acc[i][j][e] + o4[e];
                }
            }
        }
    }
}

// ---------------- round-1 fp32 fallback (ws too small) ----------------
__global__ __launch_bounds__(256) void bcc_gemm_f32(
    const float* __restrict__ x, const float* __restrict__ w,
    float* __restrict__ out) {
    __shared__ float Asf[64][68];
    __shared__ float Wsf[64][68];
    const int tid = threadIdx.x;
    const int tn = tid & 15, tm = tid >> 4;
    const int p = blockIdx.x;
    const int m0 = blockIdx.y * 64;
    const int b = m0 >> 10, r0 = m0 & 1023;
    const float* xb = x + (size_t)b * (256 * 32 * 32);
    float acc[4][4] = {};
    for (int q = 0; q < QB; ++q) {
        #pragma unroll
        for (int i = 0; i < 16; ++i) {
            int idx = i * 256 + tid;
            int s = idx & 63, mm = idx >> 6;
            int flat = (r0 + mm) * QK + q * 64 + s;
            int feat = flat >> 10, loc = flat & 1023;
            int c = feat / 9, kk = feat - c * 9;
            int hi = (loc >> 5) + (kk / 3) - 1;
            int wi = (loc & 31) + (kk % 3) - 1;
            float v = 0.0f;
            if ((unsigned)hi < 32u && (unsigned)wi < 32u)
                v = xb[(c * 32 + hi) * 32 + wi];
            Asf[mm][s] = v;
        }
        const float* wb = w + (p * QB + q) * 64;
        #pragma unroll
        for (int i = 0; i < 16; ++i) {
            int idx = i * 256 + tid;
            int t = idx & 63, s = idx >> 6;
            Wsf[s][t] = wb[(t - s) & 63];
        }
        __syncthreads();
        #pragma unroll
        for (int s0 = 0; s0 < 64; s0 += 4) {
            float4 a4[4], b4[4];
            #pragma unroll
            for (int i2 = 0; i2 < 4; ++i2)
                a4[i2] = *(const float4*)&Asf[tm * 4 + i2][s0];
            #pragma unroll
            for (int ss = 0; ss < 4; ++ss)
                b4[ss] = *(const float4*)&Wsf[s0 + ss][tn * 4];
            #pragma unroll
            for (int i2 = 0; i2 < 4; ++i2) {
                const float* av = (const float*)&a4[i2];
                #pragma unroll
                for (int ss = 0; ss < 4; ++ss) {
                    float a = av[ss];
                    acc[i2][0] += a * b4[ss].x;
                    acc[i2][1] += a * b4[ss].y;
                    acc[i2][2] += a * b4[ss].z;
                    acc[i2][3] += a * b4[ss].w;
                }
            }
        }
        __syncthreads();
    }
    float* outb = out + (size_t)b * NOC * 1024;
    const int r_base = r0 + tm * 4;
    #pragma unroll
    for (int j = 0; j < 4; ++j) {
        int oc = p * 64 + tn * 4 + j;
        float4 v = make_float4(acc[0][j], acc[1][j], acc[2][j], acc[3][j]);
        *(float4*)&outb[(size_t)oc * 1024 + r_base] = v;
    }
}

extern "C" void kernel_launch(void* const* d_in, const int* in_sizes, int n_in,
                              void* d_out, int out_size, void* d_ws, size_t ws_size,
                              hipStream_t stream) {
    const float* x = (const float*)d_in[0];
    const float* w = (const float*)d_in[1];
    float* out = (float*)d_out;

    const size_t bytesA = (size_t)MROWS * QK * sizeof(ushort);  // 37,748,736
    const size_t bytesB = (size_t)NOC * QK * sizeof(ushort);    //  2,359,296

    if (ws_size >= bytesA + bytesB) {
        ushort* wsA = (ushort*)d_ws;
        ushort* wsB = (ushort*)((char*)d_ws + bytesA);
        bcc_prep<<<PREP_A_BLOCKS + PREP_B_BLOCKS, 256, 0, stream>>>(x, w, wsA, wsB);
        bcc_mfma<<<256, 512, 0, stream>>>(wsA, wsB, out);
    } else {
        bcc_gemm_f32<<<dim3(8, MROWS / 64), 256, 0, stream>>>(x, w, out);
    }
}